// Round 12
// baseline (338.239 us; speedup 1.0000x reference)
//
#include <hip/hip_runtime.h>
#include <math.h>

#define S_LEN   4096
#define NHEADS  16
#define NKVH    4
#define HDIM    64
#define QKV_N   1536
#define HID2    2048
#define OUT_N   1024
#define QSCALE  0.18033688011112042f   // 0.125 * log2(e), folded for exp2 attn

typedef __attribute__((ext_vector_type(8))) __bf16 bf16x8;
typedef __attribute__((ext_vector_type(4))) __bf16 bf16x4;
typedef __attribute__((ext_vector_type(4))) float  f32x4;
typedef __attribute__((ext_vector_type(16))) float f32x16;
typedef __attribute__((ext_vector_type(4))) unsigned int u32x4;

// async global->LDS, 16B per lane; LDS dest is wave-uniform base + lane*16.
#define GL_LDS16(gaddr, laddr)                                                  \
  __builtin_amdgcn_global_load_lds(                                             \
      (const __attribute__((address_space(1))) unsigned int*)(gaddr),           \
      (__attribute__((address_space(3))) unsigned int*)(laddr), 16, 0, 0)

// packed f32x2 -> bf16x2 (no builtin on gfx950; T12 recipe)
__device__ __forceinline__ unsigned cvt_pk_bf16(float lo, float hi) {
  unsigned r;
  asm("v_cvt_pk_bf16_f32 %0, %1, %2" : "=v"(r) : "v"(lo), "v"(hi));
  return r;
}

// ---------------------------------------------------------------------------
// Lean f32->bf16 converts (separate launch — R4-R6: fusing costs VGPR).
// ---------------------------------------------------------------------------
__global__ __launch_bounds__(256) void cvt_all(const float* __restrict__ hid,
                                               const float* __restrict__ wq,
                                               const float* __restrict__ wo,
                                               __bf16* __restrict__ hid_bf,
                                               __bf16* __restrict__ wq_bf,
                                               __bf16* __restrict__ wo_bf) {
  const int n1 = S_LEN * HID2;
  const int n2 = QKV_N * HID2;
  int i = (blockIdx.x * blockDim.x + threadIdx.x) * 8;
  const float* src; __bf16* dst; int off;
  if (i < n1)           { src = hid; dst = hid_bf; off = i; }
  else if (i < n1 + n2) { src = wq;  dst = wq_bf;  off = i - n1; }
  else                  { src = wo;  dst = wo_bf;  off = i - n1 - n2; }
  float4 a = *(const float4*)(src + off);
  float4 b = *(const float4*)(src + off + 4);
  bf16x8 o = {(__bf16)a.x,(__bf16)a.y,(__bf16)a.z,(__bf16)a.w,
              (__bf16)b.x,(__bf16)b.y,(__bf16)b.z,(__bf16)b.w};
  *(bf16x8*)(dst + off) = o;
}

// ---------------------------------------------------------------------------
// RoPE angle table (fp64, exact vs np reference; separate lean launch).
// Must run BEFORE the QKV GEMM (its epilogue consumes ct/st).
// ---------------------------------------------------------------------------
__global__ __launch_bounds__(256) void rope_table(const int* __restrict__ positions,
                                                  float* __restrict__ ct,
                                                  float* __restrict__ st) {
  int i = blockIdx.x * blockDim.x + threadIdx.x;   // S*32
  int s = i >> 5, d = i & 31;
  double inv = pow(10000.0, -(double)d / 32.0);
  double fr = (double)positions[s] * inv;
  ct[i] = (float)cos(fr);
  st[i] = (float)sin(fr);
}

// ---------------------------------------------------------------------------
// m97-structure MFMA GEMM, double-buffered LDS, BK=64 as TWO proven BK=32
// panels, ONE barrier per 64 of K (R10-proven).  BM=64 for both GEMMs (R11:
// BM=128 neutral at our grid shapes — reverted).
// EPI: 0 = f32 C to Cp (out-proj);
//      2 = fused QKV epilogue: bn<8 -> RoPE*QSCALE -> qd [S][1024];
//          bn 8-9 -> RoPE*1.0 -> kd [S][256]; bn 10-11 -> bf16 -> Cp (V).
// RoPE pairing: acc[tm][tn] and acc[tm][tn+2] hold (x1,x2) = cols (d, d+32).
// ---------------------------------------------------------------------------
template<int BM, int EPI>
__global__ __launch_bounds__(256, (BM > 64 ? 2 : 3))
void gemm_db(const __bf16* __restrict__ A,
             const __bf16* __restrict__ B,
             void* __restrict__ Cp,
             const float* __restrict__ ct,
             const float* __restrict__ st,
             __bf16* __restrict__ qd,
             __bf16* __restrict__ kd,
             int M, int N, int K) {
  constexpr int TM  = BM / 32;
  constexpr int ASZ = BM * 32;     // one A panel (elements)
  constexpr int BSZ = 128 * 32;    // one B panel (elements)
  __shared__ __align__(16) __bf16 As[2 * 2 * ASZ];
  __shared__ __align__(16) __bf16 Bs[2 * 2 * BSZ];
  const int tid  = threadIdx.x;
  const int bm   = blockIdx.x, bn = blockIdx.y;
  const int wave = tid >> 6, lane = tid & 63;
  const int quad = lane >> 4, col = lane & 15;
  const int wm = (wave >> 1) * (BM / 2), wn = (wave & 1) * 64;

  const int lrow = lane >> 2, lcol = (lane & 3) * 8;
  const __bf16* Ag = A + (size_t)(bm * BM + wave * (BM / 4) + lrow) * K + lcol;
  const __bf16* Bg = B + (size_t)(bn * 128 + wave * 32 + lrow) * K + lcol;
  __bf16* AsW = As + wave * (BM / 4) * 32;
  __bf16* BsW = Bs + wave * 32 * 32;

  f32x4 acc[TM][4];
#pragma unroll
  for (int i = 0; i < TM; ++i)
#pragma unroll
    for (int j = 0; j < 4; ++j) acc[i][j] = (f32x4){0.f, 0.f, 0.f, 0.f};

  // stage both panels of K-tile kk into buffer `buf`
  auto stage = [&](int buf, int kk) {
#pragma unroll
    for (int p = 0; p < 2; ++p) {
      const int koff = kk + p * 32;
      __bf16* ad = AsW + (buf * 2 + p) * ASZ;
      __bf16* bd = BsW + (buf * 2 + p) * BSZ;
#pragma unroll
      for (int u = 0; u < BM / 64; ++u)
        GL_LDS16(Ag + koff + (size_t)(u * 16) * K, ad + u * 16 * 32);
      GL_LDS16(Bg + koff,                  bd);
      GL_LDS16(Bg + koff + (size_t)16 * K, bd + 16 * 32);
    }
  };

  // prologue: stage K-tile 0 into buf 0
  stage(0, 0);
  __syncthreads();

  int cur = 0;
  for (int kk = 0; kk < K; kk += 64) {
    if (kk + 64 < K) stage(cur ^ 1, kk + 64);

#pragma unroll
    for (int p = 0; p < 2; ++p) {
      const int pb = cur * 2 + p;
      bf16x8 a[TM], b[4];
#pragma unroll
      for (int tm = 0; tm < TM; ++tm)
        a[tm] = *(const bf16x8*)&As[pb * ASZ + (wm + tm * 16 + col) * 32 + quad * 8];
#pragma unroll
      for (int tn = 0; tn < 4; ++tn)
        b[tn] = *(const bf16x8*)&Bs[pb * BSZ + (wn + tn * 16 + col) * 32 + quad * 8];
#pragma unroll
      for (int tm = 0; tm < TM; ++tm)
#pragma unroll
        for (int tn = 0; tn < 4; ++tn)
          acc[tm][tn] = __builtin_amdgcn_mfma_f32_16x16x32_bf16(a[tm], b[tn], acc[tm][tn], 0, 0, 0);
    }

    __syncthreads();   // stage(nxt) landed; all reads of cur done
    cur ^= 1;
  }

  if constexpr (EPI == 2) {
    if (bn < 10) {
      // RoPE epilogue for Q (bn<8) and K (bn 8-9)
      const float scl = (bn < 8) ? QSCALE : 1.0f;
      __bf16* dst    = (bn < 8) ? qd : kd;
      const int strd = (bn < 8) ? 1024 : 256;
      const int base = (bn < 8) ? 0 : 1024;
#pragma unroll
      for (int tm = 0; tm < TM; ++tm)
#pragma unroll
        for (int tn = 0; tn < 2; ++tn) {
          const int row0 = bm * BM + wm + tm * 16 + quad * 4;
          const int cg   = bn * 128 + wn + tn * 16 + col;
          const int dcol = cg - base;
          const int d    = tn * 16 + col;           // in-head rot index, 0..31
#pragma unroll
          for (int r = 0; r < 4; ++r) {
            const int srow = row0 + r;
            float c  = ct[srow * 32 + d];
            float sn = st[srow * 32 + d];
            float x1 = acc[tm][tn][r], x2 = acc[tm][tn + 2][r];
            dst[(size_t)srow * strd + dcol]      = (__bf16)((x1 * c - x2 * sn) * scl);
            dst[(size_t)srow * strd + dcol + 32] = (__bf16)((x2 * c + x1 * sn) * scl);
          }
        }
    } else {
      // V: plain bf16 into qkv buffer (consumed by v_transpose)
#pragma unroll
      for (int tm = 0; tm < TM; ++tm)
#pragma unroll
        for (int tn = 0; tn < 4; ++tn) {
          int row = bm * BM + wm + tm * 16 + quad * 4;
          int cg  = bn * 128 + wn + tn * 16 + col;
#pragma unroll
          for (int r = 0; r < 4; ++r)
            ((__bf16*)Cp)[(size_t)(row + r) * N + cg] = (__bf16)acc[tm][tn][r];
        }
    }
  } else {
#pragma unroll
    for (int tm = 0; tm < TM; ++tm)
#pragma unroll
      for (int tn = 0; tn < 4; ++tn) {
        int row = bm * BM + wm + tm * 16 + quad * 4;
        int cg  = bn * 128 + wn + tn * 16 + col;
#pragma unroll
        for (int r = 0; r < 4; ++r)
          ((float*)Cp)[(size_t)(row + r) * N + cg] = acc[tm][tn][r];
      }
  }
}

// ---------------------------------------------------------------------------
// V transpose (lean separate launch, R1-proven).
// ---------------------------------------------------------------------------
__global__ __launch_bounds__(256) void v_transpose(const __bf16* __restrict__ qkv,
                                                   __bf16* __restrict__ vT) {
  __shared__ __align__(16) __bf16 Ts[64][72];
  const int sb = blockIdx.x, kvh = blockIdx.y, t = threadIdx.x;
  const int r = t >> 2, c16 = (t & 3) * 16;
  const __bf16* src = qkv + (size_t)(sb * 64 + r) * QKV_N + 1280 + kvh * 64 + c16;
  bf16x8 v0 = *(const bf16x8*)src;
  bf16x8 v1 = *(const bf16x8*)(src + 8);
#pragma unroll
  for (int u = 0; u < 8; ++u) {
    Ts[c16 + u][r]     = v0[u];
    Ts[c16 + 8 + u][r] = v1[u];
  }
  __syncthreads();
  __bf16* dst = vT + ((size_t)kvh * 64 + r) * S_LEN + sb * 64 + c16;
  *(bf16x8*)dst       = *(const bf16x8*)&Ts[r][c16];
  *(bf16x8*)(dst + 8) = *(const bf16x8*)&Ts[r][c16 + 8];
}

// ---------------------------------------------------------------------------
// Flash attention — R20: XOR-swizzled stride-64 K/V LDS (32768 B total,
// exactly 5 blocks/CU) + R4's <=16-tile chunk grid (16,80) = 1280 blocks =
// exactly the new residency capacity, ALL resident at t=0 -> makespan ~16
// tile-steps (vs 32 at 4/CU).  Swizzle: element-col ^ ((row&7)<<3), applied
// on BOTH the ds_write staging and the ds_read frags (no global_load_lds in
// this kernel).  Frag-read rows are k*32+r31 and 32%8==0, so the read-side
// XOR is the lane-constant (r31&7)<<3.  <=2-way bank aliasing (free, m136).
// Body otherwise R7-proven: dbuf, 1 barrier/tile, in-reg softmax->P, exp2,
// hoisted fz.  4 partial slots; op2/op3 only hold rows >=2048/>=3072 so
// their real footprints (4MB/2MB) fit in d_out after q_bf/k_bf.
// Layouts (mfma_f32_32x32x16_bf16):
//   A-frag: lane holds A[l&31][(l>>5)*8 + j];  B-frag: B[(l>>5)*8 + j][l&31]
//   C/D:    col = l&31, row = (reg&3) + 8*(reg>>2) + 4*(l>>5)
// ---------------------------------------------------------------------------
__global__ __launch_bounds__(256, 5) void attn_split(const __bf16* __restrict__ qg,
                                                     const __bf16* __restrict__ kg,
                                                     const __bf16* __restrict__ vg,
                                                     __bf16* __restrict__ op0,
                                                     __bf16* __restrict__ op1,
                                                     __bf16* __restrict__ op2,
                                                     __bf16* __restrict__ op3,
                                                     float* __restrict__ lp) {
  __shared__ __align__(16) __bf16 lds[16384];   // 32768 B exactly
  __bf16* Ks = lds;            // [2][64][64] swizzled
  __bf16* Vs = lds + 8192;     // [2][64][64] swizzled

  const int tid = threadIdx.x;
  const int h = blockIdx.x;
  const int y = blockIdx.y;                  // 0..79 (R4 chunk map)
  int qb, c;
  if (y < 8)       { qb = y;                    c = 0; }
  else if (y < 24) { qb = 8  + ((y - 8) >> 1);  c = (y - 8) & 1; }
  else if (y < 48) { qb = 16 + (y - 24) / 3;    c = (y - 24) % 3; }
  else             { qb = 24 + ((y - 48) >> 2); c = (y - 48) & 3; }
  const int n   = 2 * (qb + 1);              // causally-needed 64-key tiles
  const int nch = (qb >> 3) + 1;             // 1..4 chunks, each <= 16 tiles
  const int bsz = n / nch, rm = n - bsz * nch;
  const int kt0 = c * bsz + (c < rm ? c : rm);
  const int ktEnd = kt0 + bsz + (c < rm ? 1 : 0);

  const int kvh = h >> 2;
  const int wave = tid >> 6, lane = tid & 63;
  const int r31 = lane & 31, hi = lane >> 5;
  const int hi4 = hi * 4, hi8 = hi * 8;
  const int lsw = (r31 & 7) << 3;            // lane-constant read-side XOR
  const int qbase = qb * 128 + wave * 32;

  // Stage Q [128][64] through the LDS (swizzled stride-64), consumed into
  // registers before the main loop overwrites it.
  {
    const int r = tid >> 1, cc = (tid & 1) * 32;
    const int rx = (r & 7) << 3;
    const __bf16* src = qg + (size_t)(qb * 128 + r) * 1024 + h * 64 + cc;
    __bf16* dq = lds + ((r * 64) & 8191);    // rows 0..127 wrap across Ks+Vs
    // rows 0..127 * 64 elems = 8192 elems = 16384 B; lds holds 16384 elems.
    dq = lds + r * 64;                       // full 128*64 = 8192 elems fits
    *(bf16x8*)(dq + (( cc       ) ^ rx)) = *(const bf16x8*)(src);
    *(bf16x8*)(dq + ((cc + 8 ) ^ rx))    = *(const bf16x8*)(src + 8);
    *(bf16x8*)(dq + ((cc + 16) ^ rx))    = *(const bf16x8*)(src + 16);
    *(bf16x8*)(dq + ((cc + 24) ^ rx))    = *(const bf16x8*)(src + 24);
  }

  const int sr = tid >> 2, se = (tid & 3) * 16;
  const int ssw = (sr & 7) << 3;             // staging-row XOR
  const __bf16* kptr = kg + (size_t)sr * 256 + kvh * 64 + se;
  const __bf16* vptr = vg + ((size_t)kvh * 64 + sr) * S_LEN + se;
  bf16x8 kr0 = *(const bf16x8*)(kptr + (size_t)kt0 * 64 * 256);
  bf16x8 kr1 = *(const bf16x8*)(kptr + (size_t)kt0 * 64 * 256 + 8);
  bf16x8 vr0 = *(const bf16x8*)(vptr + (size_t)kt0 * 64);
  bf16x8 vr1 = *(const bf16x8*)(vptr + (size_t)kt0 * 64 + 8);

  __syncthreads();

  // Q B-frags: lane holds Q[wave*32 + (l&31)][dc*16 + hi*8 .. +7]
  bf16x8 qf[4];
#pragma unroll
  for (int dc = 0; dc < 4; ++dc)
    qf[dc] = *(const bf16x8*)&lds[(wave * 32 + r31) * 64 + ((dc * 16 + hi8) ^ lsw)];

  __syncthreads();   // Q region about to be overwritten by K/V staging

  f32x16 fz;
#pragma unroll
  for (int g = 0; g < 16; ++g) fz[g] = 0.f;

  f32x16 o[2];
  o[0] = fz; o[1] = fz;
  float lacc = 0.f;

  for (int kt = kt0; kt < ktEnd; ++kt) {
    const int cur = (kt - kt0) & 1;
    {
      __bf16* kd = Ks + cur * 4096 + sr * 64;
      *(bf16x8*)(kd + ( se      ^ ssw)) = kr0;
      *(bf16x8*)(kd + ((se + 8) ^ ssw)) = kr1;
      __bf16* vd = Vs + cur * 4096 + sr * 64;
      *(bf16x8*)(vd + ( se      ^ ssw)) = vr0;
      *(bf16x8*)(vd + ((se + 8) ^ ssw)) = vr1;
    }
    if (kt + 1 < ktEnd) {
      const __bf16* kn = kptr + (size_t)(kt + 1) * 64 * 256;
      const __bf16* vn = vptr + (size_t)(kt + 1) * 64;
      kr0 = *(const bf16x8*)(kn);
      kr1 = *(const bf16x8*)(kn + 8);
      vr0 = *(const bf16x8*)(vn);
      vr1 = *(const bf16x8*)(vn + 8);
    }
    __syncthreads();

    if (kt * 64 <= qbase + 31) {
      const bool full = (kt * 64 + 63 <= qbase);
      const int thr = qbase + r31 - kt * 64;   // max allowed local key

      bf16x8 pa[4];
#pragma unroll
      for (int kb = 0; kb < 2; ++kb) {
        // QK^T quadrant: S[32 keys][32 q], over d in 4 chunks; C-in = fz
        bf16x8 kf0 = *(const bf16x8*)&Ks[cur * 4096 + (kb * 32 + r31) * 64 + (hi8 ^ lsw)];
        f32x16 sf = __builtin_amdgcn_mfma_f32_32x32x16_bf16(kf0, qf[0], fz, 0, 0, 0);
#pragma unroll
        for (int dc = 1; dc < 4; ++dc) {
          bf16x8 kf = *(const bf16x8*)&Ks[cur * 4096 + (kb * 32 + r31) * 64 + ((dc * 16 + hi8) ^ lsw)];
          sf = __builtin_amdgcn_mfma_f32_32x32x16_bf16(kf, qf[dc], sf, 0, 0, 0);
        }
        // softmax numerator (exp2; scale pre-folded) + causal mask
        float p[16];
#pragma unroll
        for (int g = 0; g < 16; ++g) {
          float e = __builtin_amdgcn_exp2f(sf[g]);
          if (!full) {
            const int krow = kb * 32 + (g & 3) + 8 * (g >> 2) + hi4;
            if (krow > thr) e = 0.f;
          }
          p[g] = e;
        }
#pragma unroll
        for (int mm = 0; mm < 4; ++mm)
          lacc += (p[4 * mm] + p[4 * mm + 1]) + (p[4 * mm + 2] + p[4 * mm + 3]);
        // pack + half-swap -> PV A-frags (keys kc*16 + hi*8 + j at fixed q)
#pragma unroll
        for (int half = 0; half < 2; ++half) {
          unsigned a0 = cvt_pk_bf16(p[8 * half + 0], p[8 * half + 1]);
          unsigned a1 = cvt_pk_bf16(p[8 * half + 2], p[8 * half + 3]);
          unsigned b0 = cvt_pk_bf16(p[8 * half + 4], p[8 * half + 5]);
          unsigned b1 = cvt_pk_bf16(p[8 * half + 6], p[8 * half + 7]);
          asm("v_permlane32_swap_b32 %0, %1" : "+v"(a0), "+v"(b0));
          asm("v_permlane32_swap_b32 %0, %1" : "+v"(a1), "+v"(b1));
          u32x4 t = {a0, a1, b0, b1};
          pa[kb * 2 + half] = __builtin_bit_cast(bf16x8, t);
        }
      }

      // PV: o[q][d] += P[q][key] * V[key][d]  (Vs rows are d, cols are keys)
#pragma unroll
      for (int dt = 0; dt < 2; ++dt)
#pragma unroll
        for (int kc = 0; kc < 4; ++kc) {
          bf16x8 vf = *(const bf16x8*)&Vs[cur * 4096 + (dt * 32 + r31) * 64 + ((kc * 16 + hi8) ^ lsw)];
          o[dt] = __builtin_amdgcn_mfma_f32_32x32x16_bf16(pa[kc], vf, o[dt], 0, 0, 0);
        }
    }
  }

  // row-sum: lane and lane^32 hold complementary key-halves of the same q
  lacc += __shfl_xor(lacc, 32, 64);
  __syncthreads();
  float* lshw = (float*)lds + wave * 32;   // 512 B, K region is dead now
  if (lane < 32) lshw[lane] = lacc;
  asm volatile("s_waitcnt lgkmcnt(0)" ::: "memory");

  __bf16* op = (c == 0) ? op0 : (c == 1) ? op1 : (c == 2) ? op2 : op3;
#pragma unroll
  for (int g = 0; g < 16; ++g) {
    const int rl = (g & 3) + 8 * (g >> 2) + hi4;
    float l = lshw[rl];
    float linv = (l > 0.f) ? 1.f / l : 0.f;   // fully-masked chunk guard
    const size_t row = (size_t)(qb * 128 + wave * 32 + rl);
    op[row * 1024 + h * 64 + r31]      = (__bf16)(o[0][g] * linv);
    op[row * 1024 + h * 64 + 32 + r31] = (__bf16)(o[1][g] * linv);
  }
  if (lane < 32)
    lp[(size_t)(c * S_LEN + qb * 128 + wave * 32 + lane) * NHEADS + h] = lacc;
}

// ---------------------------------------------------------------------------
// Combine: ob = sum_c(l_c*o_c)/sum_c(l_c) over the nch(row) = row/1024 + 1
// existing chunks (R4-proven).  Sum > 0 always.  Writes ob in place over op0.
// ---------------------------------------------------------------------------
__global__ __launch_bounds__(256) void attn_combine(const __bf16* __restrict__ op0,
                                                    const __bf16* __restrict__ op1,
                                                    const __bf16* __restrict__ op2,
                                                    const __bf16* __restrict__ op3,
                                                    const float* __restrict__ lp,
                                                    __bf16* __restrict__ ob) {
  int i = blockIdx.x * 256 + threadIdx.x;   // S*128
  int row = i >> 7, c8 = (i & 127) * 8;
  int h = c8 >> 6;
  const int nch = (row >> 10) + 1;          // qb/8 + 1, uniform per row
  float l0 = lp[(size_t)row * NHEADS + h];
  float l1 = (nch > 1) ? lp[(size_t)(S_LEN + row) * NHEADS + h] : 0.f;
  float l2 = (nch > 2) ? lp[(size_t)(2 * S_LEN + row) * NHEADS + h] : 0.f;
  float l3 = (nch > 3) ? lp[(size_t)(3 * S_LEN + row) * NHEADS + h] : 0.f;
  float inv = 1.f / (l0 + l1 + l2 + l3);
  float acc[8];
  bf16x8 a = *(const bf16x8*)(op0 + (size_t)row * 1024 + c8);
#pragma unroll
  for (int u = 0; u < 8; ++u) acc[u] = (float)a[u] * l0;
  if (nch > 1) {
    bf16x8 b = *(const bf16x8*)(op1 + (size_t)row * 1024 + c8);
#pragma unroll
    for (int u = 0; u < 8; ++u) acc[u] += (float)b[u] * l1;
  }
  if (nch > 2) {
    bf16x8 b = *(const bf16x8*)(op2 + (size_t)row * 1024 + c8);
#pragma unroll
    for (int u = 0; u < 8; ++u) acc[u] += (float)b[u] * l2;
  }
  if (nch > 3) {
    bf16x8 b = *(const bf16x8*)(op3 + (size_t)row * 1024 + c8);
#pragma unroll
    for (int u = 0; u < 8; ++u) acc[u] += (float)b[u] * l3;
  }
  bf16x8 o;
#pragma unroll
  for (int u = 0; u < 8; ++u) o[u] = (__bf16)(acc[u] * inv);
  *(bf16x8*)(ob + (size_t)row * 1024 + c8) = o;
}

// ---------------------------------------------------------------------------
extern "C" void kernel_launch(void* const* d_in, const int* in_sizes, int n_in,
                              void* d_out, int out_size, void* d_ws, size_t ws_size,
                              hipStream_t stream) {
  const int*   positions = (const int*)d_in[0];
  const float* hidden    = (const float*)d_in[1];   // [4096, 2048]
  const float* w_qkv     = (const float*)d_in[2];   // [1536, 2048]
  const float* w_o       = (const float*)d_in[3];   // [1024, 1024]
  float* out = (float*)d_out;                        // [4096, 1024]

  char* ws = (char*)d_ws;
  // Peak = 40,894,464 B (proven-safe peak, unchanged).
  // ph1-2: hid_bf, wq_bf, wo_bf, ct/st          ph2-3: qkv_bf (V cols only)
  // ph2-4: q_bf/k_bf in d_out (dead until ph5)  ph3-4: vT
  // ph4:   Opart0 (over qkv), Opart1 (over wq), lpart (over qkv tail),
  //        Opart2/3 real data in d_out [12MB,16MB) / [10MB,12MB) — only
  //        rows >=2048 / >=3072 are ever touched (offset base pointers).
  // ph4b-5: attn_bf (over Opart0)
  __bf16* qkv_bf  = (__bf16*)ws;                      // [0, 12582912), V cols
  __bf16* Opart0  = (__bf16*)ws;                      // 8 MB, ph4
  __bf16* attn_bf = (__bf16*)ws;                      // ph4b-5 (in-place)
  float*  lpart   = (float*)(ws + 8388608);           // 1 MB, ph4 (qkv dead)
  __bf16* hid_bf  = (__bf16*)(ws + 12582912);         // 16 MB, ph1-2
  __bf16* vT      = (__bf16*)(ws + 23068672);         // 2 MB, ph3-4 (hid dead)
  float*  ct      = (float*)(ws + 29360128);          // 512 KB, ph1-2
  float*  st      = (float*)(ws + 29884416);          // 512 KB, ph1-2
  __bf16* wq_bf   = (__bf16*)(ws + 30408704);         // 6 MB, ph1-2
  __bf16* Opart1  = (__bf16*)(ws + 30408704);         // 8 MB, ph4 (wq dead)
  __bf16* wo_bf   = (__bf16*)(ws + 38797312);         // 2 MB, ph1-5 (ends 40894464)
  __bf16* q_bf    = (__bf16*)d_out;                   // d_out [0, 8 MB), ph2-4
  __bf16* k_bf    = (__bf16*)((char*)d_out + 8388608);// d_out [8, 10 MB), ph2-4
  // Opart3 real region d_out [10,12 MB), rows >=3072: base = 10MB - 3072*2048B
  __bf16* Opart3  = (__bf16*)((char*)d_out + 10485760 - (size_t)3072 * 2048);
  // Opart2 real region d_out [12,16 MB), rows >=2048: base = 12MB - 2048*2048B
  __bf16* Opart2  = (__bf16*)((char*)d_out + 12582912 - (size_t)2048 * 2048);

  // phase 1: converts + rope table (rope_table BEFORE gemm: epilogue uses it)
  cvt_all<<<(S_LEN * HID2 + QKV_N * HID2 + OUT_N * OUT_N) / 8 / 256, 256, 0, stream>>>(
      hidden, w_qkv, w_o, hid_bf, wq_bf, wo_bf);
  rope_table<<<S_LEN * 32 / 256, 256, 0, stream>>>(positions, ct, st);

  // phase 2: QKV projection with fused RoPE epilogue, BM=64 BK=64 dbuf
  // -> 768 blocks (3/CU)  [R10-proven config]
  gemm_db<64, 2><<<dim3(S_LEN / 64, QKV_N / 128), 256, 0, stream>>>(
      hid_bf, wq_bf, qkv_bf, ct, st, q_bf, k_bf, S_LEN, QKV_N, HID2);

  // phase 3: V transpose
  v_transpose<<<dim3(S_LEN / 64, NKVH), 256, 0, stream>>>(qkv_bf, vT);

  // phase 4: attention, <=16-tile chunks, 1280 blocks = exactly 5/CU capacity
  attn_split<<<dim3(NHEADS, 80), 256, 0, stream>>>(q_bf, k_bf, vT,
                                                   Opart0, Opart1, Opart2, Opart3,
                                                   lpart);
  attn_combine<<<S_LEN * 128 / 256, 256, 0, stream>>>(Opart0, Opart1, Opart2, Opart3,
                                                      lpart, attn_bf);

  // phase 5: output projection (f32 out), BM=64 BK=64 dbuf -> 512 blocks
  gemm_db<64, 0><<<dim3(S_LEN / 64, OUT_N / 128), 256, 0, stream>>>(
      attn_bf, wo_bf, out, nullptr, nullptr, nullptr, nullptr, S_LEN, OUT_N, OUT_N);
}

// Round 13
// 211.517 us; speedup vs baseline: 1.5991x; 1.5991x over previous
//
#include <hip/hip_runtime.h>
#include <math.h>

#define S_LEN   4096
#define NHEADS  16
#define NKVH    4
#define HDIM    64
#define QKV_N   1536
#define HID2    2048
#define OUT_N   1024
#define QSCALE  0.18033688011112042f   // 0.125 * log2(e), folded for exp2 attn

typedef __attribute__((ext_vector_type(8))) __bf16 bf16x8;
typedef __attribute__((ext_vector_type(4))) __bf16 bf16x4;
typedef __attribute__((ext_vector_type(4))) float  f32x4;
typedef __attribute__((ext_vector_type(16))) float f32x16;
typedef __attribute__((ext_vector_type(4))) unsigned int u32x4;

// async global->LDS, 16B per lane; LDS dest is wave-uniform base + lane*16.
#define GL_LDS16(gaddr, laddr)                                                  \
  __builtin_amdgcn_global_load_lds(                                             \
      (const __attribute__((address_space(1))) unsigned int*)(gaddr),           \
      (__attribute__((address_space(3))) unsigned int*)(laddr), 16, 0, 0)

// packed f32x2 -> bf16x2 (no builtin on gfx950; T12 recipe)
__device__ __forceinline__ unsigned cvt_pk_bf16(float lo, float hi) {
  unsigned r;
  asm("v_cvt_pk_bf16_f32 %0, %1, %2" : "=v"(r) : "v"(lo), "v"(hi));
  return r;
}

// ---------------------------------------------------------------------------
// Lean f32->bf16 converts (separate launch — R4-R6: fusing costs VGPR).
// ---------------------------------------------------------------------------
__global__ __launch_bounds__(256) void cvt_all(const float* __restrict__ hid,
                                               const float* __restrict__ wq,
                                               const float* __restrict__ wo,
                                               __bf16* __restrict__ hid_bf,
                                               __bf16* __restrict__ wq_bf,
                                               __bf16* __restrict__ wo_bf) {
  const int n1 = S_LEN * HID2;
  const int n2 = QKV_N * HID2;
  int i = (blockIdx.x * blockDim.x + threadIdx.x) * 8;
  const float* src; __bf16* dst; int off;
  if (i < n1)           { src = hid; dst = hid_bf; off = i; }
  else if (i < n1 + n2) { src = wq;  dst = wq_bf;  off = i - n1; }
  else                  { src = wo;  dst = wo_bf;  off = i - n1 - n2; }
  float4 a = *(const float4*)(src + off);
  float4 b = *(const float4*)(src + off + 4);
  bf16x8 o = {(__bf16)a.x,(__bf16)a.y,(__bf16)a.z,(__bf16)a.w,
              (__bf16)b.x,(__bf16)b.y,(__bf16)b.z,(__bf16)b.w};
  *(bf16x8*)(dst + off) = o;
}

// ---------------------------------------------------------------------------
// RoPE angle table (fp64, exact vs np reference; separate lean launch).
// Must run BEFORE the QKV GEMM (its epilogue consumes ct/st).
// ---------------------------------------------------------------------------
__global__ __launch_bounds__(256) void rope_table(const int* __restrict__ positions,
                                                  float* __restrict__ ct,
                                                  float* __restrict__ st) {
  int i = blockIdx.x * blockDim.x + threadIdx.x;   // S*32
  int s = i >> 5, d = i & 31;
  double inv = pow(10000.0, -(double)d / 32.0);
  double fr = (double)positions[s] * inv;
  ct[i] = (float)cos(fr);
  st[i] = (float)sin(fr);
}

// ---------------------------------------------------------------------------
// m97-structure MFMA GEMM, double-buffered LDS, BK=64 as TWO proven BK=32
// panels, ONE barrier per 64 of K (R10-proven).  BM=64 for both GEMMs.
// EPI: 0 = f32 C to Cp (out-proj);
//      2 = fused QKV epilogue: bn<8 -> RoPE*QSCALE -> qd [S][1024];
//          bn 8-9 -> RoPE*1.0 -> kd [S][256]; bn 10-11 -> bf16 -> Cp (V).
// RoPE pairing: acc[tm][tn] and acc[tm][tn+2] hold (x1,x2) = cols (d, d+32).
// ---------------------------------------------------------------------------
template<int BM, int EPI>
__global__ __launch_bounds__(256, (BM > 64 ? 2 : 3))
void gemm_db(const __bf16* __restrict__ A,
             const __bf16* __restrict__ B,
             void* __restrict__ Cp,
             const float* __restrict__ ct,
             const float* __restrict__ st,
             __bf16* __restrict__ qd,
             __bf16* __restrict__ kd,
             int M, int N, int K) {
  constexpr int TM  = BM / 32;
  constexpr int ASZ = BM * 32;     // one A panel (elements)
  constexpr int BSZ = 128 * 32;    // one B panel (elements)
  __shared__ __align__(16) __bf16 As[2 * 2 * ASZ];
  __shared__ __align__(16) __bf16 Bs[2 * 2 * BSZ];
  const int tid  = threadIdx.x;
  const int bm   = blockIdx.x, bn = blockIdx.y;
  const int wave = tid >> 6, lane = tid & 63;
  const int quad = lane >> 4, col = lane & 15;
  const int wm = (wave >> 1) * (BM / 2), wn = (wave & 1) * 64;

  const int lrow = lane >> 2, lcol = (lane & 3) * 8;
  const __bf16* Ag = A + (size_t)(bm * BM + wave * (BM / 4) + lrow) * K + lcol;
  const __bf16* Bg = B + (size_t)(bn * 128 + wave * 32 + lrow) * K + lcol;
  __bf16* AsW = As + wave * (BM / 4) * 32;
  __bf16* BsW = Bs + wave * 32 * 32;

  f32x4 acc[TM][4];
#pragma unroll
  for (int i = 0; i < TM; ++i)
#pragma unroll
    for (int j = 0; j < 4; ++j) acc[i][j] = (f32x4){0.f, 0.f, 0.f, 0.f};

  // stage both panels of K-tile kk into buffer `buf`
  auto stage = [&](int buf, int kk) {
#pragma unroll
    for (int p = 0; p < 2; ++p) {
      const int koff = kk + p * 32;
      __bf16* ad = AsW + (buf * 2 + p) * ASZ;
      __bf16* bd = BsW + (buf * 2 + p) * BSZ;
#pragma unroll
      for (int u = 0; u < BM / 64; ++u)
        GL_LDS16(Ag + koff + (size_t)(u * 16) * K, ad + u * 16 * 32);
      GL_LDS16(Bg + koff,                  bd);
      GL_LDS16(Bg + koff + (size_t)16 * K, bd + 16 * 32);
    }
  };

  // prologue: stage K-tile 0 into buf 0
  stage(0, 0);
  __syncthreads();

  int cur = 0;
  for (int kk = 0; kk < K; kk += 64) {
    if (kk + 64 < K) stage(cur ^ 1, kk + 64);

#pragma unroll
    for (int p = 0; p < 2; ++p) {
      const int pb = cur * 2 + p;
      bf16x8 a[TM], b[4];
#pragma unroll
      for (int tm = 0; tm < TM; ++tm)
        a[tm] = *(const bf16x8*)&As[pb * ASZ + (wm + tm * 16 + col) * 32 + quad * 8];
#pragma unroll
      for (int tn = 0; tn < 4; ++tn)
        b[tn] = *(const bf16x8*)&Bs[pb * BSZ + (wn + tn * 16 + col) * 32 + quad * 8];
#pragma unroll
      for (int tm = 0; tm < TM; ++tm)
#pragma unroll
        for (int tn = 0; tn < 4; ++tn)
          acc[tm][tn] = __builtin_amdgcn_mfma_f32_16x16x32_bf16(a[tm], b[tn], acc[tm][tn], 0, 0, 0);
    }

    __syncthreads();   // stage(nxt) landed; all reads of cur done
    cur ^= 1;
  }

  if constexpr (EPI == 2) {
    if (bn < 10) {
      // RoPE epilogue for Q (bn<8) and K (bn 8-9)
      const float scl = (bn < 8) ? QSCALE : 1.0f;
      __bf16* dst    = (bn < 8) ? qd : kd;
      const int strd = (bn < 8) ? 1024 : 256;
      const int base = (bn < 8) ? 0 : 1024;
#pragma unroll
      for (int tm = 0; tm < TM; ++tm)
#pragma unroll
        for (int tn = 0; tn < 2; ++tn) {
          const int row0 = bm * BM + wm + tm * 16 + quad * 4;
          const int cg   = bn * 128 + wn + tn * 16 + col;
          const int dcol = cg - base;
          const int d    = tn * 16 + col;           // in-head rot index, 0..31
#pragma unroll
          for (int r = 0; r < 4; ++r) {
            const int srow = row0 + r;
            float c  = ct[srow * 32 + d];
            float sn = st[srow * 32 + d];
            float x1 = acc[tm][tn][r], x2 = acc[tm][tn + 2][r];
            dst[(size_t)srow * strd + dcol]      = (__bf16)((x1 * c - x2 * sn) * scl);
            dst[(size_t)srow * strd + dcol + 32] = (__bf16)((x2 * c + x1 * sn) * scl);
          }
        }
    } else {
      // V: plain bf16 into qkv buffer (consumed by v_transpose)
#pragma unroll
      for (int tm = 0; tm < TM; ++tm)
#pragma unroll
        for (int tn = 0; tn < 4; ++tn) {
          int row = bm * BM + wm + tm * 16 + quad * 4;
          int cg  = bn * 128 + wn + tn * 16 + col;
#pragma unroll
          for (int r = 0; r < 4; ++r)
            ((__bf16*)Cp)[(size_t)(row + r) * N + cg] = (__bf16)acc[tm][tn][r];
        }
    }
  } else {
#pragma unroll
    for (int tm = 0; tm < TM; ++tm)
#pragma unroll
      for (int tn = 0; tn < 4; ++tn) {
        int row = bm * BM + wm + tm * 16 + quad * 4;
        int cg  = bn * 128 + wn + tn * 16 + col;
#pragma unroll
        for (int r = 0; r < 4; ++r)
          ((float*)Cp)[(size_t)(row + r) * N + cg] = acc[tm][tn][r];
      }
  }
}

// ---------------------------------------------------------------------------
// V transpose (lean separate launch, R1-proven).
// ---------------------------------------------------------------------------
__global__ __launch_bounds__(256) void v_transpose(const __bf16* __restrict__ qkv,
                                                   __bf16* __restrict__ vT) {
  __shared__ __align__(16) __bf16 Ts[64][72];
  const int sb = blockIdx.x, kvh = blockIdx.y, t = threadIdx.x;
  const int r = t >> 2, c16 = (t & 3) * 16;
  const __bf16* src = qkv + (size_t)(sb * 64 + r) * QKV_N + 1280 + kvh * 64 + c16;
  bf16x8 v0 = *(const bf16x8*)src;
  bf16x8 v1 = *(const bf16x8*)(src + 8);
#pragma unroll
  for (int u = 0; u < 8; ++u) {
    Ts[c16 + u][r]     = v0[u];
    Ts[c16 + 8 + u][r] = v1[u];
  }
  __syncthreads();
  __bf16* dst = vT + ((size_t)kvh * 64 + r) * S_LEN + sb * 64 + c16;
  *(bf16x8*)dst       = *(const bf16x8*)&Ts[r][c16];
  *(bf16x8*)(dst + 8) = *(const bf16x8*)&Ts[r][c16 + 8];
}

// ---------------------------------------------------------------------------
// Flash attention, 2-way k-split (R10-proven 59.8 us structure): dbuf K/V
// LDS stride-72 (conflict-free via 144B row rotation — stride-64 swizzle is
// geometrically incapable, R12 lesson), ONE barrier/tile, in-register
// softmax->P via cvt_pk + permlane32_swap, scalar lacc, grid (16,64)
// heavy/light pairing, exp2 path, hoisted fz.
// R13 addition: T5 s_setprio(1) around the MFMA clusters — independent
// blocks/CU at different kt phases = the m191 regime where setprio pays.
// Layouts (mfma_f32_32x32x16_bf16):
//   A-frag: lane holds A[l&31][(l>>5)*8 + j];  B-frag: B[(l>>5)*8 + j][l&31]
//   C/D:    col = l&31, row = (reg&3) + 8*(reg>>2) + 4*(l>>5)
// ---------------------------------------------------------------------------
__global__ __launch_bounds__(256, 4) void attn_split(const __bf16* __restrict__ qg,
                                                     const __bf16* __restrict__ kg,
                                                     const __bf16* __restrict__ vg,
                                                     __bf16* __restrict__ op0,
                                                     __bf16* __restrict__ op1,
                                                     float* __restrict__ lp) {
  __shared__ __align__(16) __bf16 lds[18432];   // 36864 B
  __bf16* Ks = lds;            // [2][64][72]
  __bf16* Vs = lds + 9216;     // [2][64][72]

  const int tid = threadIdx.x;
  const int h = blockIdx.x;
  const int yy = blockIdx.y;                 // 0..63
  const int qq = yy >> 1, split = yy & 1;
  const int qb = (qq < 16) ? qq : 47 - qq;   // heavy/light pairing
  const int kvh = h >> 2;
  const int wave = tid >> 6, lane = tid & 63;
  const int r31 = lane & 31, hi = lane >> 5;
  const int hi4 = hi * 4, hi8 = hi * 8;
  const int qbase = qb * 128 + wave * 32;
  const int kt0 = split * (qb + 1);
  const int ktEnd = kt0 + qb + 1;

  // Stage Q [128][64] through the K region at stride 72, consumed into
  // registers before the main loop overwrites it.
  {
    const int r = tid >> 1, c = (tid & 1) * 32;
    const __bf16* src = qg + (size_t)(qb * 128 + r) * 1024 + h * 64 + c;
    __bf16* dq = lds + r * 72 + c;
    *(bf16x8*)(dq)      = *(const bf16x8*)(src);
    *(bf16x8*)(dq + 8)  = *(const bf16x8*)(src + 8);
    *(bf16x8*)(dq + 16) = *(const bf16x8*)(src + 16);
    *(bf16x8*)(dq + 24) = *(const bf16x8*)(src + 24);
  }

  const int sr = tid >> 2, sc = (tid & 3) * 16;
  const __bf16* kptr = kg + (size_t)sr * 256 + kvh * 64 + sc;
  const __bf16* vptr = vg + ((size_t)kvh * 64 + sr) * S_LEN + sc;
  bf16x8 kr0 = *(const bf16x8*)(kptr + (size_t)kt0 * 64 * 256);
  bf16x8 kr1 = *(const bf16x8*)(kptr + (size_t)kt0 * 64 * 256 + 8);
  bf16x8 vr0 = *(const bf16x8*)(vptr + (size_t)kt0 * 64);
  bf16x8 vr1 = *(const bf16x8*)(vptr + (size_t)kt0 * 64 + 8);

  __syncthreads();

  // Q B-frags: lane holds Q[wave*32 + (l&31)][dc*16 + hi*8 .. +7]
  bf16x8 qf[4];
#pragma unroll
  for (int dc = 0; dc < 4; ++dc)
    qf[dc] = *(const bf16x8*)&lds[(wave * 32 + r31) * 72 + dc * 16 + hi8];

  __syncthreads();   // Q region about to be overwritten by K staging

  f32x16 fz;
#pragma unroll
  for (int g = 0; g < 16; ++g) fz[g] = 0.f;

  f32x16 o[2];
  o[0] = fz; o[1] = fz;
  float lacc = 0.f;

  for (int kt = kt0; kt < ktEnd; ++kt) {
    const int cur = (kt - kt0) & 1;
    {
      __bf16* kd = Ks + cur * 4608 + sr * 72 + sc;
      *(bf16x8*)kd       = kr0;
      *(bf16x8*)(kd + 8) = kr1;
      __bf16* vd = Vs + cur * 4608 + sr * 72 + sc;
      *(bf16x8*)vd       = vr0;
      *(bf16x8*)(vd + 8) = vr1;
    }
    if (kt + 1 < ktEnd) {
      const __bf16* kn = kptr + (size_t)(kt + 1) * 64 * 256;
      const __bf16* vn = vptr + (size_t)(kt + 1) * 64;
      kr0 = *(const bf16x8*)(kn);
      kr1 = *(const bf16x8*)(kn + 8);
      vr0 = *(const bf16x8*)(vn);
      vr1 = *(const bf16x8*)(vn + 8);
    }
    __syncthreads();

    if (kt * 64 > qbase + 31) continue;

    const bool full = (kt * 64 + 63 <= qbase);
    const int thr = qbase + r31 - kt * 64;   // max allowed local key for my q

    bf16x8 pa[4];
#pragma unroll
    for (int kb = 0; kb < 2; ++kb) {
      // QK^T quadrant: S[32 keys][32 q], over d in 4 chunks; C-in = fz
      __builtin_amdgcn_s_setprio(1);
      bf16x8 kf0 = *(const bf16x8*)&Ks[cur * 4608 + (kb * 32 + r31) * 72 + hi8];
      f32x16 sf = __builtin_amdgcn_mfma_f32_32x32x16_bf16(kf0, qf[0], fz, 0, 0, 0);
#pragma unroll
      for (int dc = 1; dc < 4; ++dc) {
        bf16x8 kf = *(const bf16x8*)&Ks[cur * 4608 + (kb * 32 + r31) * 72 + dc * 16 + hi8];
        sf = __builtin_amdgcn_mfma_f32_32x32x16_bf16(kf, qf[dc], sf, 0, 0, 0);
      }
      __builtin_amdgcn_s_setprio(0);
      // softmax numerator (exp2; scale pre-folded) + causal mask
      float p[16];
#pragma unroll
      for (int g = 0; g < 16; ++g) {
        float e = __builtin_amdgcn_exp2f(sf[g]);
        if (!full) {
          const int krow = kb * 32 + (g & 3) + 8 * (g >> 2) + hi4;
          if (krow > thr) e = 0.f;
        }
        p[g] = e;
      }
#pragma unroll
      for (int m = 0; m < 4; ++m)
        lacc += (p[4 * m] + p[4 * m + 1]) + (p[4 * m + 2] + p[4 * m + 3]);
      // pack + half-swap -> PV A-frags (keys kc*16 + hi*8 + j at fixed q)
#pragma unroll
      for (int half = 0; half < 2; ++half) {
        unsigned a0 = cvt_pk_bf16(p[8 * half + 0], p[8 * half + 1]);
        unsigned a1 = cvt_pk_bf16(p[8 * half + 2], p[8 * half + 3]);
        unsigned b0 = cvt_pk_bf16(p[8 * half + 4], p[8 * half + 5]);
        unsigned b1 = cvt_pk_bf16(p[8 * half + 6], p[8 * half + 7]);
        asm("v_permlane32_swap_b32 %0, %1" : "+v"(a0), "+v"(b0));
        asm("v_permlane32_swap_b32 %0, %1" : "+v"(a1), "+v"(b1));
        u32x4 t = {a0, a1, b0, b1};
        pa[kb * 2 + half] = __builtin_bit_cast(bf16x8, t);
      }
    }

    // PV: o[q][d] += P[q][key] * V[key][d]   (Vs rows are d, cols are keys)
    __builtin_amdgcn_s_setprio(1);
#pragma unroll
    for (int dt = 0; dt < 2; ++dt)
#pragma unroll
      for (int kc = 0; kc < 4; ++kc) {
        bf16x8 vf = *(const bf16x8*)&Vs[cur * 4608 + (dt * 32 + r31) * 72 + kc * 16 + hi8];
        o[dt] = __builtin_amdgcn_mfma_f32_32x32x16_bf16(pa[kc], vf, o[dt], 0, 0, 0);
      }
    __builtin_amdgcn_s_setprio(0);
  }

  // row-sum: lane and lane^32 hold complementary key-halves of the same q
  lacc += __shfl_xor(lacc, 32, 64);
  __syncthreads();
  float* lshw = (float*)lds + wave * 32;   // 512 B, K region is dead now
  if (lane < 32) lshw[lane] = lacc;
  asm volatile("s_waitcnt lgkmcnt(0)" ::: "memory");

  __bf16* op = split ? op1 : op0;
#pragma unroll
  for (int g = 0; g < 16; ++g) {
    const int rl = (g & 3) + 8 * (g >> 2) + hi4;
    float l = lshw[rl];
    float linv = (l > 0.f) ? 1.f / l : 0.f;   // fully-masked split guard
    const size_t row = (size_t)(qb * 128 + wave * 32 + rl);
    op[row * 1024 + h * 64 + r31]      = (__bf16)(o[0][g] * linv);
    op[row * 1024 + h * 64 + 32 + r31] = (__bf16)(o[1][g] * linv);
  }
  if (lane < 32)
    lp[(size_t)(split * S_LEN + qb * 128 + wave * 32 + lane) * NHEADS + h] = lacc;
}

// ---------------------------------------------------------------------------
// Combine: ob = (l0*o0 + l1*o1)/(l0+l1). l0 > 0 always (split 0 holds the
// diagonal). Writes ob in place over op0 (same-thread read-before-write).
// ---------------------------------------------------------------------------
__global__ __launch_bounds__(256) void attn_combine(const __bf16* __restrict__ op0,
                                                    const __bf16* __restrict__ op1,
                                                    const float* __restrict__ lp,
                                                    __bf16* __restrict__ ob) {
  int i = blockIdx.x * 256 + threadIdx.x;   // S*128
  int row = i >> 7, c8 = (i & 127) * 8;
  int h = c8 >> 6;
  float l0 = lp[(size_t)row * NHEADS + h];
  float l1 = lp[(size_t)(S_LEN + row) * NHEADS + h];
  float inv = 1.f / (l0 + l1);
  float w0 = l0 * inv, w1 = l1 * inv;
  bf16x8 a = *(const bf16x8*)(op0 + (size_t)row * 1024 + c8);
  bf16x8 b = *(const bf16x8*)(op1 + (size_t)row * 1024 + c8);
  bf16x8 o;
#pragma unroll
  for (int u = 0; u < 8; ++u)
    o[u] = (__bf16)((float)a[u] * w0 + (float)b[u] * w1);
  *(bf16x8*)(ob + (size_t)row * 1024 + c8) = o;
}

// ---------------------------------------------------------------------------
extern "C" void kernel_launch(void* const* d_in, const int* in_sizes, int n_in,
                              void* d_out, int out_size, void* d_ws, size_t ws_size,
                              hipStream_t stream) {
  const int*   positions = (const int*)d_in[0];
  const float* hidden    = (const float*)d_in[1];   // [4096, 2048]
  const float* w_qkv     = (const float*)d_in[2];   // [1536, 2048]
  const float* w_o       = (const float*)d_in[3];   // [1024, 1024]
  float* out = (float*)d_out;                        // [4096, 1024]

  char* ws = (char*)d_ws;
  // Peak = 40,894,464 B (proven-safe peak, unchanged).
  // ph1-2: hid_bf, wq_bf, wo_bf, ct/st          ph2-3: qkv_bf (V cols only)
  // ph2-4: q_bf/k_bf in d_out (dead until ph5)  ph3-4: vT
  // ph4:   Opart0 (over qkv), Opart1 (over wq), lpart (over qkv tail)
  // ph4b-5: attn_bf (over Opart0)
  __bf16* qkv_bf  = (__bf16*)ws;                      // [0, 12582912), V cols
  __bf16* Opart0  = (__bf16*)ws;                      // 8 MB, ph4
  __bf16* attn_bf = (__bf16*)ws;                      // ph4b-5 (in-place)
  float*  lpart   = (float*)(ws + 8388608);           // 512 KB, ph4 (qkv dead)
  __bf16* hid_bf  = (__bf16*)(ws + 12582912);         // 16 MB, ph1-2
  __bf16* vT      = (__bf16*)(ws + 23068672);         // 2 MB, ph3-4 (hid dead)
  float*  ct      = (float*)(ws + 29360128);          // 512 KB, ph1-2
  float*  st      = (float*)(ws + 29884416);          // 512 KB, ph1-2
  __bf16* wq_bf   = (__bf16*)(ws + 30408704);         // 6 MB, ph1-2
  __bf16* Opart1  = (__bf16*)(ws + 30408704);         // 8 MB, ph4 (wq dead)
  __bf16* wo_bf   = (__bf16*)(ws + 38797312);         // 2 MB, ph1-5 (ends 40894464)
  __bf16* q_bf    = (__bf16*)d_out;                   // 8 MB of d_out, ph2-4
  __bf16* k_bf    = (__bf16*)((char*)d_out + 8388608);// 2 MB of d_out, ph2-4

  // phase 1: converts + rope table (rope_table BEFORE gemm: epilogue uses it)
  cvt_all<<<(S_LEN * HID2 + QKV_N * HID2 + OUT_N * OUT_N) / 8 / 256, 256, 0, stream>>>(
      hidden, w_qkv, w_o, hid_bf, wq_bf, wo_bf);
  rope_table<<<S_LEN * 32 / 256, 256, 0, stream>>>(positions, ct, st);

  // phase 2: QKV projection with fused RoPE epilogue, BM=64 BK=64 dbuf
  // -> 768 blocks (3/CU)  [R10-proven config]
  gemm_db<64, 2><<<dim3(S_LEN / 64, QKV_N / 128), 256, 0, stream>>>(
      hid_bf, wq_bf, qkv_bf, ct, st, q_bf, k_bf, S_LEN, QKV_N, HID2);

  // phase 3: V transpose
  v_transpose<<<dim3(S_LEN / 64, NKVH), 256, 0, stream>>>(qkv_bf, vT);

  // phase 4: attention, 2-way k-split + combine
  attn_split<<<dim3(NHEADS, 64), 256, 0, stream>>>(q_bf, k_bf, vT,
                                                   Opart0, Opart1, lpart);
  attn_combine<<<S_LEN * 128 / 256, 256, 0, stream>>>(Opart0, Opart1, lpart, attn_bf);

  // phase 5: output projection (f32 out), BM=64 BK=64 dbuf -> 512 blocks
  gemm_db<64, 0><<<dim3(S_LEN / 64, OUT_N / 128), 256, 0, stream>>>(
      attn_bf, wo_bf, out, nullptr, nullptr, nullptr, nullptr, S_LEN, OUT_N, OUT_N);
}